// Round 10
// baseline (692.451 us; speedup 1.0000x reference)
//
#include <hip/hip_runtime.h>
#include <hip/hip_cooperative_groups.h>
#include <math.h>

namespace cg = cooperative_groups;

#define Bq 16
#define Mq 2048
#define Hq 1024
#define BMQ (Bq * Mq)
#define NBLK 1024
static constexpr float THR = 0.99f;

typedef float f4v __attribute__((ext_vector_type(4)));

__device__ __forceinline__ void nt_store4(float* p, float x, float y, float z,
                                          float w) {
  f4v t = {x, y, z, w};
  __builtin_nontemporal_store(t, (f4v*)p);
}
__device__ __forceinline__ f4v nt_load4(const float* p) {
  return __builtin_nontemporal_load((const f4v*)p);
}

__device__ __forceinline__ int wave_scan(int v, int lane) {
#pragma unroll
  for (int off = 1; off < 64; off <<= 1) {
    int n = __shfl_up(v, off);
    if (lane >= off) v += n;
  }
  return v;
}

// ---------------------------------------------------------------------------
// Fused 3-phase cooperative kernel (1024 blocks x 256 threads, 4 blk/CU):
//  A: per-block nlive count + GEMV logits over 32 packed rows/block
//  B: per-batch-row prefix scans + width-1 outputs (16 working blocks)
//  C: H-wide blend + pack gather/zero-fill, 32 row-tasks/block, NT streams
// ---------------------------------------------------------------------------
__global__ __launch_bounds__(256, 4) void k_fused(
    const float* __restrict__ h, const float* __restrict__ wh,
    const float* __restrict__ accp, const float* __restrict__ rem,
    const float* __restrict__ pw, const float* __restrict__ pb,
    const int* __restrict__ run, const int* __restrict__ exin,
    const int* __restrict__ upd,
    float* __restrict__ out_hp, float* __restrict__ out_wh,
    float* __restrict__ out_acc, float* __restrict__ out_rem,
    float* __restrict__ out_run, float* __restrict__ out_exit,
    float* __restrict__ logits, int* __restrict__ rank_ws,
    float* __restrict__ peff_ws, int* __restrict__ pdest_ws) {
  cg::grid_group grid = cg::this_grid();
  int tid = threadIdx.x;
  int lane = tid & 63, wv = tid >> 6;
  int blk = blockIdx.x;

  // ---------------- Phase A: count + GEMV ----------------
  {
    int b = blk >> 6;                          // 64 blocks per batch row
    int r0 = (blk & 63) << 5;                  // 32 packed rows per block
    // nlive[b]: 2048 ints, 8 per thread (L2-resident: 16 unique rows, 128 KB)
    const int* rr = run + b * Mq;
    int c = 0;
#pragma unroll
    for (int i = 0; i < 8; ++i) c += rr[(i << 8) + tid];
#pragma unroll
    for (int off = 32; off; off >>= 1) c += __shfl_xor(c, off);
    __shared__ int s_c[4];
    if (lane == 0) s_c[wv] = c;
    __syncthreads();
    int nl = s_c[0] + s_c[1] + s_c[2] + s_c[3];
    // weight fragment hoisted once per block
    const float4* w4p = (const float4*)pw;
    float4 w[4];
#pragma unroll
    for (int k = 0; k < 4; ++k) w[k] = w4p[(k << 6) + lane];
    float bias = pb[0];
#pragma unroll
    for (int it = 0; it < 8; ++it) {
      int r = r0 + (it << 2) + wv;             // one wave per packed row
      if (r < nl) {
        const float4* hrow = (const float4*)(h + ((size_t)(b * Mq + r)) * Hq);
        float s = 0.f;
#pragma unroll
        for (int k = 0; k < 4; ++k) {
          float4 a = hrow[(k << 6) + lane];    // coalesced: lane-contiguous
          s += a.x * w[k].x + a.y * w[k].y + a.z * w[k].z + a.w * w[k].w;
        }
#pragma unroll
        for (int off = 32; off; off >>= 1) s += __shfl_xor(s, off);
        if (lane == 0) logits[b * Mq + r] = s + bias;
      }
    }
  }
  grid.sync();

  // ---------------- Phase B: scan (blocks 0..15) ----------------
  if (blk < Bq) {
    int b = blk;
    __shared__ int wsA[4], wsB[4];
    int carry_run = 0, carry_cont = 0;
    int unew = upd[0] + 1;
    for (int chunk = 0; chunk < Mq; chunk += 256) {
      int m = chunk + tid;
      int idx = b * Mq + m;
      int r = run[idx];
      // scan of run -> unpack source rank
      int incl = wave_scan(r, lane);
      if (lane == 63) wsA[wv] = incl;
      __syncthreads();
      int pre = 0, tot = 0;
#pragma unroll
      for (int i = 0; i < 4; ++i) { int t = wsA[i]; if (i < wv) pre += t; tot += t; }
      incl += pre;
      int rank = carry_run + incl - 1;          // valid only when r
      // per-slot math
      float p = 0.f;
      if (r) {
        float z = logits[b * Mq + rank];
        if (z >= 0.f) p = 1.f / (1.f + expf(-z));      // stable sigmoid,
        else { float e = expf(z); p = e / (1.f + e); } // matches jax.nn.sigmoid
      }
      float accn = accp[idx] + p;
      int cont = (int)(accn < THR) & r;
      int ex = r & (cont ^ 1);
      float diff = accn - p;                    // keep reference rounding
      float peff = cont ? p : (ex ? (1.0f - diff) : 0.0f);
      out_acc[idx] = accn;
      out_rem[idx] = rem[idx] + (ex ? peff : 0.0f);
      out_run[idx] = cont ? 1.0f : 0.0f;
      out_exit[idx] = (float)(exin[idx] + (ex ? unew : 0));
      rank_ws[idx] = r ? rank : -1;
      peff_ws[idx] = peff;
      // scan of cont -> pack dest / tail zero-fill dest
      int inclc = wave_scan(cont, lane);
      if (lane == 63) wsB[wv] = inclc;
      __syncthreads();
      int prec = 0, totc = 0;
#pragma unroll
      for (int i = 0; i < 4; ++i) { int t = wsB[i]; if (i < wv) prec += t; totc += t; }
      inclc += prec;                            // inclusive cont-count in [chunk, m]
      if (cont) {
        pdest_ws[idx] = carry_cont + inclc - 1; // packed dest in [0, nnew)
      } else {
        int zr = m - (carry_cont + inclc);      // exclusive rank among non-cont
        pdest_ws[idx] = -(Mq - 1 - zr) - 1;     // zero-fill dest from the top
      }
      carry_run += tot;
      carry_cont += totc;
    }
  }
  grid.sync();

  // ---------------- Phase C: apply ----------------
  for (int bm = blk; bm < BMQ; bm += NBLK) {
    int b = bm >> 11;                           // M = 2048
    size_t rowoff = (size_t)bm * Hq;
    int rk = rank_ws[bm];                       // independent scalar loads
    int pd = pdest_ws[bm];
    float pe = peff_ws[bm];
    f4v w4 = nt_load4(wh + rowoff + 4 * tid);
    float ax = 0.f, ay = 0.f, az = 0.f, aw = 0.f;
    float ox, oy, oz, ow;
    if (rk >= 0) {
      const float4* hrow = (const float4*)(h + ((size_t)(b * Mq + rk)) * Hq);
      float4 a = hrow[tid];
      ax = a.x; ay = a.y; az = a.z; aw = a.w;
      float q = 1.0f - pe;
      ox = ax * pe + w4.x * q;
      oy = ay * pe + w4.y * q;
      oz = az * pe + w4.z * q;
      ow = aw * pe + w4.w * q;
    } else {
      ox = w4.x; oy = w4.y; oz = w4.z; ow = w4.w;  // dead row: peff==0
    }
    nt_store4(out_wh + rowoff + 4 * tid, ox, oy, oz, ow);
    if (pd >= 0) {
      nt_store4(out_hp + (((size_t)(b * Mq + pd)) * Hq) + 4 * tid, ax, ay, az, aw);
    } else {
      int zd = -(pd + 1);
      nt_store4(out_hp + (((size_t)(b * Mq + zd)) * Hq) + 4 * tid, 0.f, 0.f, 0.f,
                0.f);
    }
  }
}

// ---------------------------------------------------------------------------
extern "C" void kernel_launch(void* const* d_in, const int* in_sizes, int n_in,
                              void* d_out, int out_size, void* d_ws, size_t ws_size,
                              hipStream_t stream) {
  const float* h    = (const float*)d_in[0];
  const float* wh   = (const float*)d_in[1];
  const float* accp = (const float*)d_in[2];
  const float* rem  = (const float*)d_in[3];
  const float* pw   = (const float*)d_in[4];
  const float* pb   = (const float*)d_in[5];
  const int*   run  = (const int*)d_in[6];
  const int*   exin = (const int*)d_in[7];
  const int*   upd  = (const int*)d_in[8];

  float* out = (float*)d_out;
  const size_t BMH = (size_t)Bq * Mq * Hq;
  const size_t BM  = (size_t)Bq * Mq;
  float* out_hp   = out;
  float* out_wh   = out + BMH;
  float* out_acc  = out + 2 * BMH;
  float* out_rem  = out_acc + BM;
  float* out_run  = out_rem + BM;
  float* out_exit = out_run + BM;

  // workspace layout (all 4B elems): 4*BM ≈ 512 KB
  float* logits  = (float*)d_ws;
  int*   rank_ws = (int*)d_ws + BM;
  float* peff_ws = (float*)d_ws + 2 * BM;
  int*   pdest_ws= (int*)d_ws + 3 * BM;

  void* kargs[] = {
      (void*)&h,       (void*)&wh,      (void*)&accp,   (void*)&rem,
      (void*)&pw,      (void*)&pb,      (void*)&run,    (void*)&exin,
      (void*)&upd,     (void*)&out_hp,  (void*)&out_wh, (void*)&out_acc,
      (void*)&out_rem, (void*)&out_run, (void*)&out_exit,
      (void*)&logits,  (void*)&rank_ws, (void*)&peff_ws, (void*)&pdest_ws};
  hipLaunchCooperativeKernel((void*)k_fused, dim3(NBLK), dim3(256), kargs, 0,
                             stream);
}